// Round 2
// baseline (498.875 us; speedup 1.0000x reference)
//
#include <hip/hip_runtime.h>

// Performer (FAVOR+) encoder block, bf16 MFMA pipeline.
// B=32 L=1024 HID=512 H=8 DH=64 FF=2048, N=32768 tokens.
//
// Workspace layout (peak ~104.1 MiB):
//   [0,32M)    qp  -> later hb (qp dead after favor_num)
//   [32M,64M)  kp  -> later attn (kp dead after favor_kv) -> later ffa chunk
//   [64M,96M)  vb  -> later ffa chunk (vb dead after favor_kv)
//   [96M,~104M) weights (wqkvT/woT/w1T/w2T), kvt, ksum, bqkv
// d_out (f32 [N,512], 64 MiB) doubles as hpre/ffpre scratch; LN2 is in-place.

#define DI __device__ __forceinline__

typedef __attribute__((ext_vector_type(8))) short bf16x8;
typedef __attribute__((ext_vector_type(4))) float f32x4;

DI float b2f(short s){ unsigned int u = ((unsigned int)(unsigned short)s) << 16; float f; __builtin_memcpy(&f, &u, 4); return f; }
DI short f2b(float f){ unsigned int u; __builtin_memcpy(&u, &f, 4); u += 0x7fffu + ((u >> 16) & 1u); return (short)(u >> 16); }

constexpr int Ll = 1024;

// ---------------- transpose + convert: in f32 [R][C] -> out bf16 [C][R] ----------------
__global__ void k_tcvt(const float* __restrict__ in, short* __restrict__ out, int R, int C){
  __shared__ float t[32][33];
  int c0 = blockIdx.x * 32, r0 = blockIdx.y * 32;
  int x = threadIdx.x, y = threadIdx.y;   // block (32,8)
  #pragma unroll
  for (int j = 0; j < 4; ++j) t[y + 8*j][x] = in[(long)(r0 + y + 8*j) * C + c0 + x];
  __syncthreads();
  #pragma unroll
  for (int j = 0; j < 4; ++j) out[(long)(c0 + y + 8*j) * R + r0 + x] = f2b(t[x][y + 8*j]);
}

__global__ void k_pack_bias(const float* __restrict__ bq, const float* __restrict__ bk,
                            const float* __restrict__ bv, float* __restrict__ bqkv){
  int i = blockIdx.x * 256 + threadIdx.x;
  if (i < 512) bqkv[i] = bq[i];
  else if (i < 1024) bqkv[i] = bk[i - 512];
  else if (i < 1536) bqkv[i] = bv[i - 1024];
}

// ---------------- generic 128x128 bf16 MFMA GEMM with fused epilogues ----------------
// A: bf16 [M,KD] row-major (or f32 if AF32, converted during staging).
// BT [ND,KD] bf16 row-major (B transposed).
// EPI: 0=QKV(phi)  1=attn-out(+bo+x -> f32)  2=FFN1(relu -> bf16)  3=FFN2(+b2+hb -> f32)
template<int EPI, int KD, bool AF32>
__global__ __launch_bounds__(256) void k_gemm(
    const void* __restrict__ Aptr, const short* __restrict__ BT,
    const float* __restrict__ bias, const float* __restrict__ residF, const short* __restrict__ residB,
    short* __restrict__ oQ, short* __restrict__ oK, short* __restrict__ oV, float* __restrict__ oF)
{
  constexpr int LS = 72;                      // 64 + 8 pad (bf16 elems)
  __shared__ short As[128 * LS];
  __shared__ short Bs[128 * LS];
  const int tid = threadIdx.x;
  const int wave = tid >> 6, lane = tid & 63;
  const int wr = wave >> 1, wc = wave & 1;    // 2x2 wave grid, each wave 64x64
  const int lg = lane >> 4, lr = lane & 15;
  const int m0 = blockIdx.x * 128, n0 = blockIdx.y * 128;

  f32x4 acc[4][4];
  #pragma unroll
  for (int i = 0; i < 4; ++i)
    #pragma unroll
    for (int j = 0; j < 4; ++j) acc[i][j] = 0.f;

  for (int k0 = 0; k0 < KD; k0 += 64) {
    __syncthreads();
    #pragma unroll
    for (int s = 0; s < 4; ++s) {             // 128x64 tile = 1024 chunks of 8 elems
      int idx = tid + s * 256;
      int row = idx >> 3, c8 = idx & 7;
      bf16x8 va;
      if constexpr (AF32) {
        const float* Af = (const float*)Aptr;
        const float4* p = (const float4*)(Af + (long)(m0 + row) * KD + k0 + c8 * 8);
        float4 a = p[0], b = p[1];
        va[0]=f2b(a.x); va[1]=f2b(a.y); va[2]=f2b(a.z); va[3]=f2b(a.w);
        va[4]=f2b(b.x); va[5]=f2b(b.y); va[6]=f2b(b.z); va[7]=f2b(b.w);
      } else {
        const short* Ab = (const short*)Aptr;
        va = *(const bf16x8*)(Ab + (long)(m0 + row) * KD + k0 + c8 * 8);
      }
      bf16x8 vb = *(const bf16x8*)(BT + (long)(n0 + row) * KD + k0 + c8 * 8);
      *(bf16x8*)(&As[row * LS + c8 * 8]) = va;
      *(bf16x8*)(&Bs[row * LS + c8 * 8]) = vb;
    }
    __syncthreads();
    #pragma unroll
    for (int kk = 0; kk < 2; ++kk) {
      bf16x8 af[4], bfr[4];
      #pragma unroll
      for (int i = 0; i < 4; ++i) {
        af[i]  = *(const bf16x8*)(&As[(wr * 64 + i * 16 + lr) * LS + kk * 32 + lg * 8]);
        bfr[i] = *(const bf16x8*)(&Bs[(wc * 64 + i * 16 + lr) * LS + kk * 32 + lg * 8]);
      }
      #pragma unroll
      for (int i = 0; i < 4; ++i)
        #pragma unroll
        for (int j = 0; j < 4; ++j)
          acc[i][j] = __builtin_amdgcn_mfma_f32_16x16x32_bf16(af[i], bfr[j], acc[i][j], 0, 0, 0);
    }
  }

  #pragma unroll
  for (int i = 0; i < 4; ++i)
    #pragma unroll
    for (int j = 0; j < 4; ++j)
      #pragma unroll
      for (int r = 0; r < 4; ++r) {
        int grow = m0 + wr * 64 + i * 16 + lg * 4 + r;   // C/D: row=(lane>>4)*4+reg
        int gcol = n0 + wc * 64 + j * 16 + lr;           //      col=lane&15
        float v = acc[i][j][r];
        if constexpr (EPI == 0) {
          v += bias[gcol];
          int which = gcol >> 9, hd = gcol & 511, h = hd >> 6, d = hd & 63;
          int b = grow >> 10, l = grow & 1023;
          long o = ((long)(b * 8 + h) * 1024 + l) * 64 + d;
          if (which == 2) oV[o] = f2b(v);
          else { float p = fmaxf(v, 0.f) + 1e-3f; if (which) oK[o] = f2b(p); else oQ[o] = f2b(p); }
        } else if constexpr (EPI == 1) {
          v += bias[gcol] + residF[(long)grow * 512 + gcol];
          oF[(long)grow * 512 + gcol] = v;
        } else if constexpr (EPI == 2) {
          v = fmaxf(v + bias[gcol], 0.f);
          oQ[(long)grow * 2048 + gcol] = f2b(v);
        } else {
          v += bias[gcol] + b2f(residB[(long)grow * 512 + gcol]);
          oF[(long)grow * 512 + gcol] = v;
        }
      }
}

// ---------------- FAVOR: kvt[bh][d][m] = sum_l kp[l][m]*v[l][d];  ksum[bh][m] ----------------
__global__ __launch_bounds__(256) void k_favor_kv(const short* __restrict__ kp, const short* __restrict__ vb,
                                                  short* __restrict__ kvt, float* __restrict__ ksum)
{
  constexpr int LS = 72;
  __shared__ short kps[64 * LS];
  __shared__ short vps[64 * LS];
  int bh = blockIdx.x;
  const short* kpp = kp + (long)bh * Ll * 64;
  const short* vpp = vb + (long)bh * Ll * 64;
  int tid = threadIdx.x;
  int mb = (tid & 15) * 4, db = (tid >> 4) * 4;
  float acc[4][4];
  float ks[4] = {0.f, 0.f, 0.f, 0.f};
  #pragma unroll
  for (int i = 0; i < 4; ++i)
    #pragma unroll
    for (int j = 0; j < 4; ++j) acc[i][j] = 0.f;

  for (int l0 = 0; l0 < Ll; l0 += 64) {
    __syncthreads();
    #pragma unroll
    for (int s = 0; s < 2; ++s) {            // 64x64 tile = 512 chunks
      int idx = tid + s * 256;
      int row = idx >> 3, c8 = idx & 7;
      *(bf16x8*)(&kps[row * LS + c8 * 8]) = *(const bf16x8*)(kpp + (long)(l0 + row) * 64 + c8 * 8);
      *(bf16x8*)(&vps[row * LS + c8 * 8]) = *(const bf16x8*)(vpp + (long)(l0 + row) * 64 + c8 * 8);
    }
    __syncthreads();
    #pragma unroll 4
    for (int l = 0; l < 64; ++l) {
      short4 ka = *(const short4*)(&kps[l * LS + mb]);
      short4 va = *(const short4*)(&vps[l * LS + db]);
      float kf[4] = {b2f(ka.x), b2f(ka.y), b2f(ka.z), b2f(ka.w)};
      float vf[4] = {b2f(va.x), b2f(va.y), b2f(va.z), b2f(va.w)};
      if (tid < 16) { ks[0] += kf[0]; ks[1] += kf[1]; ks[2] += kf[2]; ks[3] += kf[3]; }
      #pragma unroll
      for (int i = 0; i < 4; ++i)
        #pragma unroll
        for (int j = 0; j < 4; ++j) acc[i][j] += kf[i] * vf[j];
    }
  }
  #pragma unroll
  for (int i = 0; i < 4; ++i)
    #pragma unroll
    for (int j = 0; j < 4; ++j)
      kvt[((long)bh * 64 + db + j) * 64 + mb + i] = f2b(acc[i][j]);
  if (tid < 16) {
    #pragma unroll
    for (int i = 0; i < 4; ++i) ksum[bh * 64 + mb + i] = ks[i];
  }
}

// ---------------- FAVOR: attn = (qp @ kv)/den ----------------
__global__ __launch_bounds__(256) void k_favor_num(const short* __restrict__ qp, const short* __restrict__ kvt,
                                                   const float* __restrict__ ksum, short* __restrict__ attn)
{
  constexpr int LS = 72;
  __shared__ short kvs[64 * LS];
  __shared__ float part[256];
  __shared__ float den[128];
  int bh = blockIdx.x >> 3, lt = blockIdx.x & 7;
  int b = bh >> 3, h = bh & 7;
  const short* qpp = qp + ((long)bh * Ll + lt * 128) * 64;
  int tid = threadIdx.x;

  #pragma unroll
  for (int s = 0; s < 2; ++s) {
    int idx = tid + s * 256;
    int row = idx >> 3, c8 = idx & 7;
    *(bf16x8*)(&kvs[row * LS + c8 * 8]) = *(const bf16x8*)(kvt + (long)bh * 4096 + row * 64 + c8 * 8);
  }
  { // den partial: 2 threads per row, 32 features each
    int r = tid >> 1, half = tid & 1;
    const short* qr = qpp + (long)r * 64 + half * 32;
    const float* kss = ksum + bh * 64 + half * 32;
    float s = 0.f;
    #pragma unroll
    for (int c = 0; c < 4; ++c) {
      bf16x8 v = *(const bf16x8*)(qr + c * 8);
      #pragma unroll
      for (int j = 0; j < 8; ++j) s += b2f(v[j]) * kss[c * 8 + j];
    }
    part[tid] = s;
  }
  __syncthreads();
  if (tid < 128) den[tid] = part[2 * tid] + part[2 * tid + 1];
  __syncthreads();

  int wave = tid >> 6, lane = tid & 63;
  int wr = wave >> 1, wc = wave & 1;
  int lg = lane >> 4, lr = lane & 15;
  f32x4 acc[4][2];
  #pragma unroll
  for (int i = 0; i < 4; ++i) { acc[i][0] = 0.f; acc[i][1] = 0.f; }
  #pragma unroll
  for (int kk = 0; kk < 2; ++kk) {
    bf16x8 af[4], bfr[2];
    #pragma unroll
    for (int i = 0; i < 4; ++i)
      af[i] = *(const bf16x8*)(qpp + (long)(wr * 64 + i * 16 + lr) * 64 + kk * 32 + lg * 8);
    #pragma unroll
    for (int j = 0; j < 2; ++j)
      bfr[j] = *(const bf16x8*)(&kvs[(wc * 32 + j * 16 + lr) * LS + kk * 32 + lg * 8]);
    #pragma unroll
    for (int i = 0; i < 4; ++i)
      #pragma unroll
      for (int j = 0; j < 2; ++j)
        acc[i][j] = __builtin_amdgcn_mfma_f32_16x16x32_bf16(af[i], bfr[j], acc[i][j], 0, 0, 0);
  }
  #pragma unroll
  for (int i = 0; i < 4; ++i)
    #pragma unroll
    for (int j = 0; j < 2; ++j)
      #pragma unroll
      for (int r = 0; r < 4; ++r) {
        int rl = wr * 64 + i * 16 + lg * 4 + r;
        int d  = wc * 32 + j * 16 + lr;
        int t  = b * Ll + lt * 128 + rl;
        attn[(long)t * 512 + h * 64 + d] = f2b(acc[i][j][r] / den[rl]);
      }
}

// ---------------- LayerNorm: one wave per row of 512 ----------------
template<int OUTBF>
__global__ __launch_bounds__(256) void k_ln(const float* __restrict__ in, const float* __restrict__ sc,
                                            const float* __restrict__ bi, short* __restrict__ ob, float* __restrict__ of)
{
  int row = blockIdx.x * 4 + (threadIdx.x >> 6);
  int lane = threadIdx.x & 63;
  const float* r = in + (long)row * 512;
  float4 a = *(const float4*)(r + lane * 4);
  float4 b = *(const float4*)(r + 256 + lane * 4);
  float s  = a.x + a.y + a.z + a.w + b.x + b.y + b.z + b.w;
  float s2 = a.x*a.x + a.y*a.y + a.z*a.z + a.w*a.w + b.x*b.x + b.y*b.y + b.z*b.z + b.w*b.w;
  #pragma unroll
  for (int off = 32; off; off >>= 1) { s += __shfl_xor(s, off); s2 += __shfl_xor(s2, off); }
  float mu = s * (1.f / 512.f);
  float var = s2 * (1.f / 512.f) - mu * mu;
  float rstd = rsqrtf(var + 1e-6f);
  int c0 = lane * 4;
  float o0[4], o1[4];
  const float* ap = &a.x; const float* bp = &b.x;
  #pragma unroll
  for (int j = 0; j < 4; ++j) {
    o0[j] = (ap[j] - mu) * rstd * sc[c0 + j]       + bi[c0 + j];
    o1[j] = (bp[j] - mu) * rstd * sc[256 + c0 + j] + bi[256 + c0 + j];
  }
  if constexpr (OUTBF) {
    short4 w0 = {f2b(o0[0]), f2b(o0[1]), f2b(o0[2]), f2b(o0[3])};
    short4 w1 = {f2b(o1[0]), f2b(o1[1]), f2b(o1[2]), f2b(o1[3])};
    *(short4*)(ob + (long)row * 512 + c0) = w0;
    *(short4*)(ob + (long)row * 512 + 256 + c0) = w1;
  } else {
    *(float4*)(of + (long)row * 512 + c0)       = (float4){o0[0], o0[1], o0[2], o0[3]};
    *(float4*)(of + (long)row * 512 + 256 + c0) = (float4){o1[0], o1[1], o1[2], o1[3]};
  }
}

extern "C" void kernel_launch(void* const* d_in, const int* in_sizes, int n_in,
                              void* d_out, int out_size, void* d_ws, size_t ws_size,
                              hipStream_t stream)
{
  const float* x   = (const float*)d_in[0];
  const float* Wq  = (const float*)d_in[1];
  const float* bq  = (const float*)d_in[2];
  const float* Wk  = (const float*)d_in[3];
  const float* bk  = (const float*)d_in[4];
  const float* Wv  = (const float*)d_in[5];
  const float* bv  = (const float*)d_in[6];
  const float* Wo  = (const float*)d_in[7];
  const float* bo  = (const float*)d_in[8];
  const float* g1  = (const float*)d_in[9];
  const float* be1 = (const float*)d_in[10];
  const float* W1  = (const float*)d_in[11];
  const float* b1  = (const float*)d_in[12];
  const float* W2  = (const float*)d_in[13];
  const float* b2  = (const float*)d_in[14];
  const float* g2  = (const float*)d_in[15];
  const float* be2 = (const float*)d_in[16];
  float* out = (float*)d_out;

  const long MB = 1024L * 1024L;
  char* ws = (char*)d_ws;
  short* qp    = (short*)(ws + 0 * MB);     // 32 MiB [B,H,L,64]; slot later reused by hb
  short* kp    = (short*)(ws + 32 * MB);    // 32 MiB; slot later reused by attn, then ffa
  short* vb    = (short*)(ws + 64 * MB);    // 32 MiB; slot later part of ffa
  short* attn  = (short*)(ws + 32 * MB);    // 32 MiB [N,512] (kp dead)
  short* hb    = (short*)(ws + 0 * MB);     // 32 MiB [N,512] (qp dead)
  short* ffa   = (short*)(ws + 32 * MB);    // 64 MiB [16384,2048] chunk (attn+vb dead)
  short* wqkvT = (short*)(ws + 96 * MB);    // 1.5 MiB [1536,512]
  short* woT   = (short*)(ws + 98 * MB);    // 0.5 MiB [512,512]
  short* w1T   = (short*)(ws + 99 * MB);    // 2 MiB   [2048,512]
  short* w2T   = (short*)(ws + 101 * MB);   // 2 MiB   [512,2048]
  short* kvt   = (short*)(ws + 103 * MB);   // 2 MiB   [BH,64,64]
  float* ksum  = (float*)(ws + 105 * MB);   // 64 KiB  [BH,64]
  float* bqkv  = (float*)(ws + 106 * MB);   // 6 KiB
  float* hpre  = out;                       // d_out doubles as f32 scratch

  dim3 tb(32, 8);
  k_tcvt<<<dim3(16, 16), tb, 0, stream>>>(Wq, wqkvT,               512, 512);
  k_tcvt<<<dim3(16, 16), tb, 0, stream>>>(Wk, wqkvT + 512 * 512,   512, 512);
  k_tcvt<<<dim3(16, 16), tb, 0, stream>>>(Wv, wqkvT + 1024 * 512,  512, 512);
  k_tcvt<<<dim3(16, 16), tb, 0, stream>>>(Wo, woT,                 512, 512);
  k_tcvt<<<dim3(64, 16), tb, 0, stream>>>(W1, w1T,                 512, 2048);
  k_tcvt<<<dim3(16, 64), tb, 0, stream>>>(W2, w2T,                 2048, 512);
  k_pack_bias<<<6, 256, 0, stream>>>(bq, bk, bv, bqkv);

  // QKV projection (A = x f32, converted in staging)
  k_gemm<0, 512, true><<<dim3(256, 12), 256, 0, stream>>>(x, wqkvT, bqkv, nullptr, nullptr, qp, kp, vb, nullptr);
  k_favor_kv<<<256, 256, 0, stream>>>(kp, vb, kvt, ksum);
  k_favor_num<<<2048, 256, 0, stream>>>(qp, kvt, ksum, attn);
  // attn-out + residual -> hpre (= d_out)
  k_gemm<1, 512, false><<<dim3(256, 4), 256, 0, stream>>>(attn, woT, bo, x, nullptr, nullptr, nullptr, nullptr, hpre);
  k_ln<1><<<8192, 256, 0, stream>>>(hpre, g1, be1, hb, nullptr);
  // FFN in 2 chunks of 16384 rows (ffa chunk = 64 MiB)
  for (int c = 0; c < 2; ++c) {
    const short* hbc = hb + (long)c * 16384 * 512;
    k_gemm<2, 512, false><<<dim3(128, 16), 256, 0, stream>>>(hbc, w1T, b1, nullptr, nullptr, ffa, nullptr, nullptr, nullptr);
    k_gemm<3, 2048, false><<<dim3(128, 4), 256, 0, stream>>>(ffa, w2T, b2, nullptr, hbc, nullptr, nullptr, nullptr, hpre + (long)c * 16384 * 512);
  }
  k_ln<0><<<8192, 256, 0, stream>>>(hpre, g2, be2, nullptr, out);
}

// Round 3
// 476.588 us; speedup vs baseline: 1.0468x; 1.0468x over previous
//
#include <hip/hip_runtime.h>

// Performer (FAVOR+) encoder block, bf16 MFMA pipeline. Round 3:
//  - 1D grid + XCD-aware swizzle (n-fastest per XCD m-chunk) on all GEMMs
//  - global_load_lds(16B) staging, linear LDS [128][64] with both-sides XOR swizzle
//  - favor_num Q-tile staged via global_load_lds
// B=32 L=1024 HID=512 H=8 DH=64 FF=2048, N=32768 tokens.

#define DI __device__ __forceinline__
#define AS1 __attribute__((address_space(1)))
#define AS3 __attribute__((address_space(3)))
#define GLD16(g, l) __builtin_amdgcn_global_load_lds((const AS1 void*)(g), (AS3 void*)(l), 16, 0, 0)

typedef __attribute__((ext_vector_type(8))) short bf16x8;
typedef __attribute__((ext_vector_type(4))) float f32x4;

DI float b2f(short s){ unsigned int u = ((unsigned int)(unsigned short)s) << 16; float f; __builtin_memcpy(&f, &u, 4); return f; }
DI short f2b(float f){ unsigned int u; __builtin_memcpy(&u, &f, 4); u += 0x7fffu + ((u >> 16) & 1u); return (short)(u >> 16); }

constexpr int Ll = 1024;

// ---------------- transpose + convert: in f32 [R][C] -> out bf16 [C][R] ----------------
__global__ void k_tcvt(const float* __restrict__ in, short* __restrict__ out, int R, int C){
  __shared__ float t[32][33];
  int c0 = blockIdx.x * 32, r0 = blockIdx.y * 32;
  int x = threadIdx.x, y = threadIdx.y;   // block (32,8)
  #pragma unroll
  for (int j = 0; j < 4; ++j) t[y + 8*j][x] = in[(long)(r0 + y + 8*j) * C + c0 + x];
  __syncthreads();
  #pragma unroll
  for (int j = 0; j < 4; ++j) out[(long)(c0 + y + 8*j) * R + r0 + x] = f2b(t[x][y + 8*j]);
}

__global__ void k_pack_bias(const float* __restrict__ bq, const float* __restrict__ bk,
                            const float* __restrict__ bv, float* __restrict__ bqkv){
  int i = blockIdx.x * 256 + threadIdx.x;
  if (i < 512) bqkv[i] = bq[i];
  else if (i < 1024) bqkv[i] = bk[i - 512];
  else if (i < 1536) bqkv[i] = bv[i - 1024];
}

// ---------------- 128x128 bf16 MFMA GEMM, gload_lds + XOR-swizzled LDS ----------------
// A: bf16 [M,KD] row-major (or f32 if AF32, converted during staging).
// BT [NT*128,KD] bf16 row-major (B transposed).
// Grid: 1D, G = MT*NT blocks (G % 8 == 0). XCD swizzle: wg = (bid&7)*(G/8) + bid>>3,
// then mt = wg/NT (m-chunk contiguous per XCD), nt = wg%NT (fastest -> A-panel L2 reuse).
// LDS layout: linear [128 rows][64 bf16], 16B slot s of row r holds global chunk s^(r&7).
// EPI: 0=QKV(phi)  1=attn-out(+bo+x -> f32)  2=FFN1(relu -> bf16)  3=FFN2(+b2+hb -> f32)
template<int EPI, int KD, bool AF32>
__global__ __launch_bounds__(256) void k_gemm(
    const void* __restrict__ Aptr, const short* __restrict__ BT, int NT,
    const float* __restrict__ bias, const float* __restrict__ residF, const short* __restrict__ residB,
    short* __restrict__ oQ, short* __restrict__ oK, short* __restrict__ oV, float* __restrict__ oF)
{
  __shared__ short As[128 * 64];
  __shared__ short Bs[128 * 64];
  const int tid = threadIdx.x;
  const int wave = tid >> 6, lane = tid & 63;
  const int wr = wave >> 1, wc = wave & 1;    // 2x2 wave grid, each wave 64x64
  const int lg = lane >> 4, lr = lane & 15;
  const int lrow = lane >> 3;                 // 0..7 within the wave's 8-row window
  const int lslot = (lane & 7) ^ lrow;        // inverse-swizzled source chunk

  const int per = gridDim.x >> 3;
  const int wg = (blockIdx.x & 7) * per + (blockIdx.x >> 3);
  const long m0 = (long)(wg / NT) * 128, n0 = (long)(wg % NT) * 128;

  f32x4 acc[4][4];
  #pragma unroll
  for (int i = 0; i < 4; ++i)
    #pragma unroll
    for (int j = 0; j < 4; ++j) acc[i][j] = 0.f;

  for (int k0 = 0; k0 < KD; k0 += 64) {
    __syncthreads();
    if constexpr (AF32) {
      #pragma unroll
      for (int s = 0; s < 4; ++s) {           // B tile via gload_lds
        int rs = (s * 4 + wave) * 8;
        GLD16(BT + (n0 + rs + lrow) * KD + k0 + lslot * 8, &Bs[rs * 64]);
      }
      const float* Af = (const float*)Aptr;
      #pragma unroll
      for (int s = 0; s < 4; ++s) {           // A tile: f32 -> bf16, swizzled ds_write
        int idx = tid + s * 256;
        int row = idx >> 3, c = idx & 7;
        const float4* p = (const float4*)(Af + (m0 + row) * KD + k0 + c * 8);
        float4 a = p[0], b = p[1];
        bf16x8 va;
        va[0]=f2b(a.x); va[1]=f2b(a.y); va[2]=f2b(a.z); va[3]=f2b(a.w);
        va[4]=f2b(b.x); va[5]=f2b(b.y); va[6]=f2b(b.z); va[7]=f2b(b.w);
        *(bf16x8*)((char*)As + row * 128 + ((c * 16) ^ ((row & 7) << 4))) = va;
      }
    } else {
      const short* Ab = (const short*)Aptr;
      #pragma unroll
      for (int s = 0; s < 4; ++s) {
        int rs = (s * 4 + wave) * 8;
        GLD16(Ab + (m0 + rs + lrow) * KD + k0 + lslot * 8, &As[rs * 64]);
        GLD16(BT + (n0 + rs + lrow) * KD + k0 + lslot * 8, &Bs[rs * 64]);
      }
    }
    __syncthreads();
    #pragma unroll
    for (int kk = 0; kk < 2; ++kk) {
      bf16x8 af[4], bfr[4];
      #pragma unroll
      for (int i = 0; i < 4; ++i) {
        int ra = wr * 64 + i * 16 + lr;
        int rb = wc * 64 + i * 16 + lr;
        af[i]  = *(const bf16x8*)((const char*)As + ra * 128 + ((kk * 64 + lg * 16) ^ ((ra & 7) << 4)));
        bfr[i] = *(const bf16x8*)((const char*)Bs + rb * 128 + ((kk * 64 + lg * 16) ^ ((rb & 7) << 4)));
      }
      #pragma unroll
      for (int i = 0; i < 4; ++i)
        #pragma unroll
        for (int j = 0; j < 4; ++j)
          acc[i][j] = __builtin_amdgcn_mfma_f32_16x16x32_bf16(af[i], bfr[j], acc[i][j], 0, 0, 0);
    }
  }

  #pragma unroll
  for (int i = 0; i < 4; ++i)
    #pragma unroll
    for (int j = 0; j < 4; ++j)
      #pragma unroll
      for (int r = 0; r < 4; ++r) {
        int grow = (int)m0 + wr * 64 + i * 16 + lg * 4 + r;   // C/D: row=(lane>>4)*4+reg
        int gcol = (int)n0 + wc * 64 + j * 16 + lr;           //      col=lane&15
        float v = acc[i][j][r];
        if constexpr (EPI == 0) {
          v += bias[gcol];
          int which = gcol >> 9, hd = gcol & 511, h = hd >> 6, d = hd & 63;
          int b = grow >> 10, l = grow & 1023;
          long o = ((long)(b * 8 + h) * 1024 + l) * 64 + d;
          if (which == 2) oV[o] = f2b(v);
          else { float p = fmaxf(v, 0.f) + 1e-3f; if (which) oK[o] = f2b(p); else oQ[o] = f2b(p); }
        } else if constexpr (EPI == 1) {
          v += bias[gcol] + residF[(long)grow * 512 + gcol];
          oF[(long)grow * 512 + gcol] = v;
        } else if constexpr (EPI == 2) {
          v = fmaxf(v + bias[gcol], 0.f);
          oQ[(long)grow * 2048 + gcol] = f2b(v);
        } else {
          v += bias[gcol] + b2f(residB[(long)grow * 512 + gcol]);
          oF[(long)grow * 512 + gcol] = v;
        }
      }
}

// ---------------- FAVOR: kvt[bh][d][m] = sum_l kp[l][m]*v[l][d];  ksum[bh][m] ----------------
__global__ __launch_bounds__(256) void k_favor_kv(const short* __restrict__ kp, const short* __restrict__ vb,
                                                  short* __restrict__ kvt, float* __restrict__ ksum)
{
  constexpr int LS = 72;
  __shared__ short kps[64 * LS];
  __shared__ short vps[64 * LS];
  int bh = blockIdx.x;
  const short* kpp = kp + (long)bh * Ll * 64;
  const short* vpp = vb + (long)bh * Ll * 64;
  int tid = threadIdx.x;
  int mb = (tid & 15) * 4, db = (tid >> 4) * 4;
  float acc[4][4];
  float ks[4] = {0.f, 0.f, 0.f, 0.f};
  #pragma unroll
  for (int i = 0; i < 4; ++i)
    #pragma unroll
    for (int j = 0; j < 4; ++j) acc[i][j] = 0.f;

  for (int l0 = 0; l0 < Ll; l0 += 64) {
    __syncthreads();
    #pragma unroll
    for (int s = 0; s < 2; ++s) {            // 64x64 tile = 512 chunks
      int idx = tid + s * 256;
      int row = idx >> 3, c8 = idx & 7;
      *(bf16x8*)(&kps[row * LS + c8 * 8]) = *(const bf16x8*)(kpp + (long)(l0 + row) * 64 + c8 * 8);
      *(bf16x8*)(&vps[row * LS + c8 * 8]) = *(const bf16x8*)(vpp + (long)(l0 + row) * 64 + c8 * 8);
    }
    __syncthreads();
    #pragma unroll 4
    for (int l = 0; l < 64; ++l) {
      short4 ka = *(const short4*)(&kps[l * LS + mb]);
      short4 va = *(const short4*)(&vps[l * LS + db]);
      float kf[4] = {b2f(ka.x), b2f(ka.y), b2f(ka.z), b2f(ka.w)};
      float vf[4] = {b2f(va.x), b2f(va.y), b2f(va.z), b2f(va.w)};
      if (tid < 16) { ks[0] += kf[0]; ks[1] += kf[1]; ks[2] += kf[2]; ks[3] += kf[3]; }
      #pragma unroll
      for (int i = 0; i < 4; ++i)
        #pragma unroll
        for (int j = 0; j < 4; ++j) acc[i][j] += kf[i] * vf[j];
    }
  }
  #pragma unroll
  for (int i = 0; i < 4; ++i)
    #pragma unroll
    for (int j = 0; j < 4; ++j)
      kvt[((long)bh * 64 + db + j) * 64 + mb + i] = f2b(acc[i][j]);
  if (tid < 16) {
    #pragma unroll
    for (int i = 0; i < 4; ++i) ksum[bh * 64 + mb + i] = ks[i];
  }
}

// ---------------- FAVOR: attn = (qp @ kv)/den ----------------
__global__ __launch_bounds__(256) void k_favor_num(const short* __restrict__ qp, const short* __restrict__ kvt,
                                                   const float* __restrict__ ksum, short* __restrict__ attn)
{
  constexpr int LS = 72;
  __shared__ short Qs[128 * 64];      // swizzled, staged via gload_lds
  __shared__ short kvs[64 * LS];
  __shared__ float part[256];
  __shared__ float den[128];
  int bh = blockIdx.x >> 3, lt = blockIdx.x & 7;
  int b = bh >> 3, h = bh & 7;
  const short* qpp = qp + ((long)bh * Ll + lt * 128) * 64;
  int tid = threadIdx.x;
  int wave = tid >> 6, lane = tid & 63;
  int lrow = lane >> 3, lslot = (lane & 7) ^ lrow;

  #pragma unroll
  for (int s = 0; s < 4; ++s) {       // Q tile 128x64 via gload_lds
    int rs = (s * 4 + wave) * 8;
    GLD16(qpp + (long)(rs + lrow) * 64 + lslot * 8, &Qs[rs * 64]);
  }
  #pragma unroll
  for (int s = 0; s < 2; ++s) {       // kv tile (reg-staged, padded)
    int idx = tid + s * 256;
    int row = idx >> 3, c8 = idx & 7;
    *(bf16x8*)(&kvs[row * LS + c8 * 8]) = *(const bf16x8*)(kvt + (long)bh * 4096 + row * 64 + c8 * 8);
  }
  __syncthreads();
  { // den partial: 2 threads per row, 32 features each (reads swizzled Qs)
    int r = tid >> 1, half = tid & 1;
    const float* kss = ksum + bh * 64 + half * 32;
    float s = 0.f;
    #pragma unroll
    for (int c = 0; c < 4; ++c) {
      int cc = half * 4 + c;
      bf16x8 v = *(const bf16x8*)((const char*)Qs + r * 128 + ((cc * 16) ^ ((r & 7) << 4)));
      #pragma unroll
      for (int j = 0; j < 8; ++j) s += b2f(v[j]) * kss[c * 8 + j];
    }
    part[tid] = s;
  }
  __syncthreads();
  if (tid < 128) den[tid] = part[2 * tid] + part[2 * tid + 1];
  __syncthreads();

  int wr = wave >> 1, wc = wave & 1;
  int lg = lane >> 4, lr = lane & 15;
  f32x4 acc[4][2];
  #pragma unroll
  for (int i = 0; i < 4; ++i) { acc[i][0] = 0.f; acc[i][1] = 0.f; }
  #pragma unroll
  for (int kk = 0; kk < 2; ++kk) {
    bf16x8 af[4], bfr[2];
    #pragma unroll
    for (int i = 0; i < 4; ++i) {
      int ra = wr * 64 + i * 16 + lr;
      af[i] = *(const bf16x8*)((const char*)Qs + ra * 128 + ((kk * 64 + lg * 16) ^ ((ra & 7) << 4)));
    }
    #pragma unroll
    for (int j = 0; j < 2; ++j)
      bfr[j] = *(const bf16x8*)(&kvs[(wc * 32 + j * 16 + lr) * LS + kk * 32 + lg * 8]);
    #pragma unroll
    for (int i = 0; i < 4; ++i)
      #pragma unroll
      for (int j = 0; j < 2; ++j)
        acc[i][j] = __builtin_amdgcn_mfma_f32_16x16x32_bf16(af[i], bfr[j], acc[i][j], 0, 0, 0);
  }
  #pragma unroll
  for (int i = 0; i < 4; ++i)
    #pragma unroll
    for (int j = 0; j < 2; ++j)
      #pragma unroll
      for (int r = 0; r < 4; ++r) {
        int rl = wr * 64 + i * 16 + lg * 4 + r;
        int d  = wc * 32 + j * 16 + lr;
        int t  = b * Ll + lt * 128 + rl;
        attn[(long)t * 512 + h * 64 + d] = f2b(acc[i][j][r] / den[rl]);
      }
}

// ---------------- LayerNorm: one wave per row of 512 ----------------
template<int OUTBF>
__global__ __launch_bounds__(256) void k_ln(const float* __restrict__ in, const float* __restrict__ sc,
                                            const float* __restrict__ bi, short* __restrict__ ob, float* __restrict__ of)
{
  int row = blockIdx.x * 4 + (threadIdx.x >> 6);
  int lane = threadIdx.x & 63;
  const float* r = in + (long)row * 512;
  float4 a = *(const float4*)(r + lane * 4);
  float4 b = *(const float4*)(r + 256 + lane * 4);
  float s  = a.x + a.y + a.z + a.w + b.x + b.y + b.z + b.w;
  float s2 = a.x*a.x + a.y*a.y + a.z*a.z + a.w*a.w + b.x*b.x + b.y*b.y + b.z*b.z + b.w*b.w;
  #pragma unroll
  for (int off = 32; off; off >>= 1) { s += __shfl_xor(s, off); s2 += __shfl_xor(s2, off); }
  float mu = s * (1.f / 512.f);
  float var = s2 * (1.f / 512.f) - mu * mu;
  float rstd = rsqrtf(var + 1e-6f);
  int c0 = lane * 4;
  float o0[4], o1[4];
  const float* ap = &a.x; const float* bp = &b.x;
  #pragma unroll
  for (int j = 0; j < 4; ++j) {
    o0[j] = (ap[j] - mu) * rstd * sc[c0 + j]       + bi[c0 + j];
    o1[j] = (bp[j] - mu) * rstd * sc[256 + c0 + j] + bi[256 + c0 + j];
  }
  if constexpr (OUTBF) {
    short4 w0 = {f2b(o0[0]), f2b(o0[1]), f2b(o0[2]), f2b(o0[3])};
    short4 w1 = {f2b(o1[0]), f2b(o1[1]), f2b(o1[2]), f2b(o1[3])};
    *(short4*)(ob + (long)row * 512 + c0) = w0;
    *(short4*)(ob + (long)row * 512 + 256 + c0) = w1;
  } else {
    *(float4*)(of + (long)row * 512 + c0)       = (float4){o0[0], o0[1], o0[2], o0[3]};
    *(float4*)(of + (long)row * 512 + 256 + c0) = (float4){o1[0], o1[1], o1[2], o1[3]};
  }
}

extern "C" void kernel_launch(void* const* d_in, const int* in_sizes, int n_in,
                              void* d_out, int out_size, void* d_ws, size_t ws_size,
                              hipStream_t stream)
{
  const float* x   = (const float*)d_in[0];
  const float* Wq  = (const float*)d_in[1];
  const float* bq  = (const float*)d_in[2];
  const float* Wk  = (const float*)d_in[3];
  const float* bk  = (const float*)d_in[4];
  const float* Wv  = (const float*)d_in[5];
  const float* bv  = (const float*)d_in[6];
  const float* Wo  = (const float*)d_in[7];
  const float* bo  = (const float*)d_in[8];
  const float* g1  = (const float*)d_in[9];
  const float* be1 = (const float*)d_in[10];
  const float* W1  = (const float*)d_in[11];
  const float* b1  = (const float*)d_in[12];
  const float* W2  = (const float*)d_in[13];
  const float* b2  = (const float*)d_in[14];
  const float* g2  = (const float*)d_in[15];
  const float* be2 = (const float*)d_in[16];
  float* out = (float*)d_out;

  const long MB = 1024L * 1024L;
  char* ws = (char*)d_ws;
  short* qp    = (short*)(ws + 0 * MB);     // 32 MiB [B,H,L,64]; slot later reused by hb
  short* kp    = (short*)(ws + 32 * MB);    // 32 MiB; slot later reused by attn, then ffa
  short* vb    = (short*)(ws + 64 * MB);    // 32 MiB; slot later part of ffa
  short* attn  = (short*)(ws + 32 * MB);    // 32 MiB [N,512] (kp dead)
  short* hb    = (short*)(ws + 0 * MB);     // 32 MiB [N,512] (qp dead)
  short* ffa   = (short*)(ws + 32 * MB);    // 64 MiB [16384,2048] chunk (attn+vb dead)
  short* wqkvT = (short*)(ws + 96 * MB);    // 1.5 MiB [1536,512]
  short* woT   = (short*)(ws + 98 * MB);    // 0.5 MiB [512,512]
  short* w1T   = (short*)(ws + 99 * MB);    // 2 MiB   [2048,512]
  short* w2T   = (short*)(ws + 101 * MB);   // 2 MiB   [512,2048]
  short* kvt   = (short*)(ws + 103 * MB);   // 2 MiB   [BH,64,64]
  float* ksum  = (float*)(ws + 105 * MB);   // 64 KiB  [BH,64]
  float* bqkv  = (float*)(ws + 106 * MB);   // 6 KiB
  float* hpre  = out;                       // d_out doubles as f32 scratch

  dim3 tb(32, 8);
  k_tcvt<<<dim3(16, 16), tb, 0, stream>>>(Wq, wqkvT,               512, 512);
  k_tcvt<<<dim3(16, 16), tb, 0, stream>>>(Wk, wqkvT + 512 * 512,   512, 512);
  k_tcvt<<<dim3(16, 16), tb, 0, stream>>>(Wv, wqkvT + 1024 * 512,  512, 512);
  k_tcvt<<<dim3(16, 16), tb, 0, stream>>>(Wo, woT,                 512, 512);
  k_tcvt<<<dim3(64, 16), tb, 0, stream>>>(W1, w1T,                 512, 2048);
  k_tcvt<<<dim3(16, 64), tb, 0, stream>>>(W2, w2T,                 2048, 512);
  k_pack_bias<<<6, 256, 0, stream>>>(bq, bk, bv, bqkv);

  // QKV projection (A = x f32, converted in staging): grid 256x12 -> 3072
  k_gemm<0, 512, true><<<3072, 256, 0, stream>>>(x, wqkvT, 12, bqkv, nullptr, nullptr, qp, kp, vb, nullptr);
  k_favor_kv<<<256, 256, 0, stream>>>(kp, vb, kvt, ksum);
  k_favor_num<<<2048, 256, 0, stream>>>(qp, kvt, ksum, attn);
  // attn-out + residual -> hpre (= d_out): grid 256x4 -> 1024
  k_gemm<1, 512, false><<<1024, 256, 0, stream>>>(attn, woT, 4, bo, x, nullptr, nullptr, nullptr, nullptr, hpre);
  k_ln<1><<<8192, 256, 0, stream>>>(hpre, g1, be1, hb, nullptr);
  // FFN in 2 chunks of 16384 rows (ffa chunk = 64 MiB)
  for (int c = 0; c < 2; ++c) {
    const short* hbc = hb + (long)c * 16384 * 512;
    k_gemm<2, 512, false><<<2048, 256, 0, stream>>>(hbc, w1T, 16, b1, nullptr, nullptr, ffa, nullptr, nullptr, nullptr);
    k_gemm<3, 2048, false><<<512, 256, 0, stream>>>(ffa, w2T, 4, b2, nullptr, hbc, nullptr, nullptr, nullptr, hpre + (long)c * 16384 * 512);
  }
  k_ln<0><<<8192, 256, 0, stream>>>(hpre, g2, be2, nullptr, out);
}

// Round 4
// 430.704 us; speedup vs baseline: 1.1583x; 1.1065x over previous
//
#include <hip/hip_runtime.h>

// Performer (FAVOR+) encoder block, bf16 MFMA pipeline. Round 4:
//  - xb = bf16(x) precomputed once (in d_out scratch); QKV uses pure-bf16 gload_lds path
//  - favor_kv split over 4 L-chunks (1024 blocks) + reduce kernel (occupancy fix)
//  - attn-out epilogue writes bf16 h_pre; LN1 reads bf16 (k_ln_bb)
//  - merged 512x512 weight transposes into one kernel
// B=32 L=1024 HID=512 H=8 DH=64 FF=2048, N=32768 tokens.
//
// ws (<=106.1 MiB):
//   [0,32M)   qp  -> hb after favor_num
//   [32M,64M) kp  -> attn after favor_kv -> ffa (lower half)
//   [64M,96M) vb  -> hpreB after favor   -> ffa (upper half) after LN1
//   [96M,..)  wqkvT, woT, w1T, w2T, kvt, ksum, bqkv
// d_out (64 MiB f32): [0,32M) xb scratch; [32M,48.25M) favor partials;
//   fully overwritten by FFN2 + LN2 at the end.

#define DI __device__ __forceinline__
#define AS1 __attribute__((address_space(1)))
#define AS3 __attribute__((address_space(3)))
#define GLD16(g, l) __builtin_amdgcn_global_load_lds((const AS1 void*)(g), (AS3 void*)(l), 16, 0, 0)

typedef __attribute__((ext_vector_type(8))) short bf16x8;
typedef __attribute__((ext_vector_type(4))) float f32x4;

DI float b2f(short s){ unsigned int u = ((unsigned int)(unsigned short)s) << 16; float f; __builtin_memcpy(&f, &u, 4); return f; }
DI short f2b(float f){ unsigned int u; __builtin_memcpy(&u, &f, 4); u += 0x7fffu + ((u >> 16) & 1u); return (short)(u >> 16); }

constexpr int Ll = 1024;

// ---------------- x -> bf16 ----------------
__global__ __launch_bounds__(256) void k_cvt_x(const float* __restrict__ x, short* __restrict__ xb){
  long i = (long)blockIdx.x * 256 + threadIdx.x;           // one bf16x8 per thread
  const float4* p = (const float4*)x + i * 2;
  float4 a = p[0], b = p[1];
  bf16x8 o;
  o[0]=f2b(a.x); o[1]=f2b(a.y); o[2]=f2b(a.z); o[3]=f2b(a.w);
  o[4]=f2b(b.x); o[5]=f2b(b.y); o[6]=f2b(b.z); o[7]=f2b(b.w);
  *((bf16x8*)xb + i) = o;
}

// ---------------- transpose + convert: in f32 [R][C] -> out bf16 [C][R] ----------------
__global__ void k_tcvt(const float* __restrict__ in, short* __restrict__ out, int R, int C){
  __shared__ float t[32][33];
  int c0 = blockIdx.x * 32, r0 = blockIdx.y * 32;
  int x = threadIdx.x, y = threadIdx.y;   // block (32,8)
  #pragma unroll
  for (int j = 0; j < 4; ++j) t[y + 8*j][x] = in[(long)(r0 + y + 8*j) * C + c0 + x];
  __syncthreads();
  #pragma unroll
  for (int j = 0; j < 4; ++j) out[(long)(c0 + y + 8*j) * R + r0 + x] = f2b(t[x][y + 8*j]);
}

// 4x [512,512] transposes in one launch (z picks matrix)
__global__ void k_tcvt4(const float* __restrict__ s0, const float* __restrict__ s1,
                        const float* __restrict__ s2, const float* __restrict__ s3,
                        short* __restrict__ d0, short* __restrict__ d1,
                        short* __restrict__ d2, short* __restrict__ d3){
  __shared__ float t[32][33];
  int z = blockIdx.z;
  const float* in = z == 0 ? s0 : z == 1 ? s1 : z == 2 ? s2 : s3;
  short* out      = z == 0 ? d0 : z == 1 ? d1 : z == 2 ? d2 : d3;
  int c0 = blockIdx.x * 32, r0 = blockIdx.y * 32;
  int x = threadIdx.x, y = threadIdx.y;   // block (32,8)
  #pragma unroll
  for (int j = 0; j < 4; ++j) t[y + 8*j][x] = in[(long)(r0 + y + 8*j) * 512 + c0 + x];
  __syncthreads();
  #pragma unroll
  for (int j = 0; j < 4; ++j) out[(long)(c0 + y + 8*j) * 512 + r0 + x] = f2b(t[x][y + 8*j]);
}

__global__ void k_pack_bias(const float* __restrict__ bq, const float* __restrict__ bk,
                            const float* __restrict__ bv, float* __restrict__ bqkv){
  int i = blockIdx.x * 256 + threadIdx.x;
  if (i < 512) bqkv[i] = bq[i];
  else if (i < 1024) bqkv[i] = bk[i - 512];
  else if (i < 1536) bqkv[i] = bv[i - 1024];
}

// ---------------- 128x128 bf16 MFMA GEMM, gload_lds + XOR-swizzled LDS ----------------
// A [M,KD] bf16 row-major, BT [NT*128,KD] bf16 row-major (B transposed).
// Grid: 1D, G = MT*NT (G % 8 == 0). XCD swizzle: wg = (bid&7)*(G/8)+bid>>3; m-chunk
// contiguous per XCD, nt fastest (A-panel L2 reuse).
// LDS: linear [128][64] bf16; 16B slot s of row r holds global chunk s^(r&7).
// EPI: 0=QKV(phi->qp,kp,vb)  1=attn-out(+bo+x -> bf16)  2=FFN1(relu->bf16)  3=FFN2(+b2+hb->f32)
template<int EPI, int KD>
__global__ __launch_bounds__(256) void k_gemm(
    const short* __restrict__ A, const short* __restrict__ BT, int NT,
    const float* __restrict__ bias, const float* __restrict__ residF, const short* __restrict__ residB,
    short* __restrict__ oQ, short* __restrict__ oK, short* __restrict__ oV, float* __restrict__ oF)
{
  __shared__ short As[128 * 64];
  __shared__ short Bs[128 * 64];
  const int tid = threadIdx.x;
  const int wave = tid >> 6, lane = tid & 63;
  const int wr = wave >> 1, wc = wave & 1;    // 2x2 wave grid, each wave 64x64
  const int lg = lane >> 4, lr = lane & 15;
  const int lrow = lane >> 3;                 // 0..7 within the wave's 8-row window
  const int lslot = (lane & 7) ^ lrow;        // inverse-swizzled source chunk

  const int per = gridDim.x >> 3;
  const int wg = (blockIdx.x & 7) * per + (blockIdx.x >> 3);
  const long m0 = (long)(wg / NT) * 128, n0 = (long)(wg % NT) * 128;

  f32x4 acc[4][4];
  #pragma unroll
  for (int i = 0; i < 4; ++i)
    #pragma unroll
    for (int j = 0; j < 4; ++j) acc[i][j] = 0.f;

  for (int k0 = 0; k0 < KD; k0 += 64) {
    __syncthreads();
    #pragma unroll
    for (int s = 0; s < 4; ++s) {
      int rs = (s * 4 + wave) * 8;
      GLD16(A  + (m0 + rs + lrow) * KD + k0 + lslot * 8, &As[rs * 64]);
      GLD16(BT + (n0 + rs + lrow) * KD + k0 + lslot * 8, &Bs[rs * 64]);
    }
    __syncthreads();
    #pragma unroll
    for (int kk = 0; kk < 2; ++kk) {
      bf16x8 af[4], bfr[4];
      #pragma unroll
      for (int i = 0; i < 4; ++i) {
        int ra = wr * 64 + i * 16 + lr;
        int rb = wc * 64 + i * 16 + lr;
        af[i]  = *(const bf16x8*)((const char*)As + ra * 128 + ((kk * 64 + lg * 16) ^ ((ra & 7) << 4)));
        bfr[i] = *(const bf16x8*)((const char*)Bs + rb * 128 + ((kk * 64 + lg * 16) ^ ((rb & 7) << 4)));
      }
      #pragma unroll
      for (int i = 0; i < 4; ++i)
        #pragma unroll
        for (int j = 0; j < 4; ++j)
          acc[i][j] = __builtin_amdgcn_mfma_f32_16x16x32_bf16(af[i], bfr[j], acc[i][j], 0, 0, 0);
    }
  }

  #pragma unroll
  for (int i = 0; i < 4; ++i)
    #pragma unroll
    for (int j = 0; j < 4; ++j)
      #pragma unroll
      for (int r = 0; r < 4; ++r) {
        int grow = (int)m0 + wr * 64 + i * 16 + lg * 4 + r;   // C/D: row=(lane>>4)*4+reg
        int gcol = (int)n0 + wc * 64 + j * 16 + lr;           //      col=lane&15
        float v = acc[i][j][r];
        if constexpr (EPI == 0) {
          v += bias[gcol];
          int which = gcol >> 9, hd = gcol & 511, h = hd >> 6, d = hd & 63;
          int b = grow >> 10, l = grow & 1023;
          long o = ((long)(b * 8 + h) * 1024 + l) * 64 + d;
          if (which == 2) oV[o] = f2b(v);
          else { float p = fmaxf(v, 0.f) + 1e-3f; if (which) oK[o] = f2b(p); else oQ[o] = f2b(p); }
        } else if constexpr (EPI == 1) {
          v += bias[gcol] + residF[(long)grow * 512 + gcol];
          oQ[(long)grow * 512 + gcol] = f2b(v);
        } else if constexpr (EPI == 2) {
          v = fmaxf(v + bias[gcol], 0.f);
          oQ[(long)grow * 2048 + gcol] = f2b(v);
        } else {
          v += bias[gcol] + b2f(residB[(long)grow * 512 + gcol]);
          oF[(long)grow * 512 + gcol] = v;
        }
      }
}

// ---------------- FAVOR kv partials: chunk c sums l in [c*256, c*256+256) ----------------
// kvp[c][bh][d][m] f32, ksp[c][bh][m] f32
__global__ __launch_bounds__(256) void k_fkv_part(const short* __restrict__ kp, const short* __restrict__ vb,
                                                  float* __restrict__ kvp, float* __restrict__ ksp)
{
  constexpr int LS = 72;
  __shared__ short kps[64 * LS];
  __shared__ short vps[64 * LS];
  int bh = blockIdx.x & 255, c = blockIdx.x >> 8;
  const short* kpp = kp + (long)bh * Ll * 64;
  const short* vpp = vb + (long)bh * Ll * 64;
  int tid = threadIdx.x;
  int mb = (tid & 15) * 4, db = (tid >> 4) * 4;
  float acc[4][4];
  float ks[4] = {0.f, 0.f, 0.f, 0.f};
  #pragma unroll
  for (int i = 0; i < 4; ++i)
    #pragma unroll
    for (int j = 0; j < 4; ++j) acc[i][j] = 0.f;

  for (int l0 = c * 256; l0 < c * 256 + 256; l0 += 64) {
    __syncthreads();
    #pragma unroll
    for (int s = 0; s < 2; ++s) {            // 64x64 tile = 512 chunks
      int idx = tid + s * 256;
      int row = idx >> 3, c8 = idx & 7;
      *(bf16x8*)(&kps[row * LS + c8 * 8]) = *(const bf16x8*)(kpp + (long)(l0 + row) * 64 + c8 * 8);
      *(bf16x8*)(&vps[row * LS + c8 * 8]) = *(const bf16x8*)(vpp + (long)(l0 + row) * 64 + c8 * 8);
    }
    __syncthreads();
    #pragma unroll 4
    for (int l = 0; l < 64; ++l) {
      short4 ka = *(const short4*)(&kps[l * LS + mb]);
      short4 va = *(const short4*)(&vps[l * LS + db]);
      float kf[4] = {b2f(ka.x), b2f(ka.y), b2f(ka.z), b2f(ka.w)};
      float vf[4] = {b2f(va.x), b2f(va.y), b2f(va.z), b2f(va.w)};
      if (tid < 16) { ks[0] += kf[0]; ks[1] += kf[1]; ks[2] += kf[2]; ks[3] += kf[3]; }
      #pragma unroll
      for (int i = 0; i < 4; ++i)
        #pragma unroll
        for (int j = 0; j < 4; ++j) acc[i][j] += kf[i] * vf[j];
    }
  }
  float* kout = kvp + (long)c * 1048576 + (long)bh * 4096;
  #pragma unroll
  for (int i = 0; i < 4; ++i)
    #pragma unroll
    for (int j = 0; j < 4; ++j)
      kout[(db + j) * 64 + mb + i] = acc[i][j];
  if (tid < 16) {
    #pragma unroll
    for (int i = 0; i < 4; ++i) ksp[(long)c * 16384 + bh * 64 + mb + i] = ks[i];
  }
}

__global__ __launch_bounds__(256) void k_fkv_reduce(const float* __restrict__ kvp, const float* __restrict__ ksp,
                                                    short* __restrict__ kvt, float* __restrict__ ksum)
{
  int g = blockIdx.x * 256 + threadIdx.x;   // 1048576 total
  float s = kvp[g] + kvp[g + 1048576] + kvp[g + 2 * 1048576] + kvp[g + 3 * 1048576];
  kvt[g] = f2b(s);
  if (g < 16384)
    ksum[g] = ksp[g] + ksp[g + 16384] + ksp[g + 2 * 16384] + ksp[g + 3 * 16384];
}

// ---------------- FAVOR: attn = (qp @ kv)/den ----------------
__global__ __launch_bounds__(256) void k_favor_num(const short* __restrict__ qp, const short* __restrict__ kvt,
                                                   const float* __restrict__ ksum, short* __restrict__ attn)
{
  constexpr int LS = 72;
  __shared__ short Qs[128 * 64];      // swizzled, staged via gload_lds
  __shared__ short kvs[64 * LS];
  __shared__ float part[256];
  __shared__ float den[128];
  int bh = blockIdx.x >> 3, lt = blockIdx.x & 7;
  int b = bh >> 3, h = bh & 7;
  const short* qpp = qp + ((long)bh * Ll + lt * 128) * 64;
  int tid = threadIdx.x;
  int wave = tid >> 6, lane = tid & 63;
  int lrow = lane >> 3, lslot = (lane & 7) ^ lrow;

  #pragma unroll
  for (int s = 0; s < 4; ++s) {       // Q tile 128x64 via gload_lds
    int rs = (s * 4 + wave) * 8;
    GLD16(qpp + (long)(rs + lrow) * 64 + lslot * 8, &Qs[rs * 64]);
  }
  #pragma unroll
  for (int s = 0; s < 2; ++s) {       // kv tile (reg-staged, padded)
    int idx = tid + s * 256;
    int row = idx >> 3, c8 = idx & 7;
    *(bf16x8*)(&kvs[row * LS + c8 * 8]) = *(const bf16x8*)(kvt + (long)bh * 4096 + row * 64 + c8 * 8);
  }
  __syncthreads();
  { // den partial: 2 threads per row, 32 features each (reads swizzled Qs)
    int r = tid >> 1, half = tid & 1;
    const float* kss = ksum + bh * 64 + half * 32;
    float s = 0.f;
    #pragma unroll
    for (int c = 0; c < 4; ++c) {
      int cc = half * 4 + c;
      bf16x8 v = *(const bf16x8*)((const char*)Qs + r * 128 + ((cc * 16) ^ ((r & 7) << 4)));
      #pragma unroll
      for (int j = 0; j < 8; ++j) s += b2f(v[j]) * kss[c * 8 + j];
    }
    part[tid] = s;
  }
  __syncthreads();
  if (tid < 128) den[tid] = part[2 * tid] + part[2 * tid + 1];
  __syncthreads();

  int wr = wave >> 1, wc = wave & 1;
  int lg = lane >> 4, lr = lane & 15;
  f32x4 acc[4][2];
  #pragma unroll
  for (int i = 0; i < 4; ++i) { acc[i][0] = 0.f; acc[i][1] = 0.f; }
  #pragma unroll
  for (int kk = 0; kk < 2; ++kk) {
    bf16x8 af[4], bfr[2];
    #pragma unroll
    for (int i = 0; i < 4; ++i) {
      int ra = wr * 64 + i * 16 + lr;
      af[i] = *(const bf16x8*)((const char*)Qs + ra * 128 + ((kk * 64 + lg * 16) ^ ((ra & 7) << 4)));
    }
    #pragma unroll
    for (int j = 0; j < 2; ++j)
      bfr[j] = *(const bf16x8*)(&kvs[(wc * 32 + j * 16 + lr) * LS + kk * 32 + lg * 8]);
    #pragma unroll
    for (int i = 0; i < 4; ++i)
      #pragma unroll
      for (int j = 0; j < 2; ++j)
        acc[i][j] = __builtin_amdgcn_mfma_f32_16x16x32_bf16(af[i], bfr[j], acc[i][j], 0, 0, 0);
  }
  #pragma unroll
  for (int i = 0; i < 4; ++i)
    #pragma unroll
    for (int j = 0; j < 2; ++j)
      #pragma unroll
      for (int r = 0; r < 4; ++r) {
        int rl = wr * 64 + i * 16 + lg * 4 + r;
        int d  = wc * 32 + j * 16 + lr;
        int t  = b * Ll + lt * 128 + rl;
        attn[(long)t * 512 + h * 64 + d] = f2b(acc[i][j][r] / den[rl]);
      }
}

// ---------------- LayerNorm, bf16 in -> bf16 out (one wave per row of 512) ----------------
__global__ __launch_bounds__(256) void k_ln_bb(const short* __restrict__ in, const float* __restrict__ sc,
                                               const float* __restrict__ bi, short* __restrict__ ob)
{
  int row = blockIdx.x * 4 + (threadIdx.x >> 6);
  int lane = threadIdx.x & 63;
  bf16x8 v = *((const bf16x8*)(in + (long)row * 512) + lane);
  float e[8];
  #pragma unroll
  for (int j = 0; j < 8; ++j) e[j] = b2f(v[j]);
  float s = 0.f, s2 = 0.f;
  #pragma unroll
  for (int j = 0; j < 8; ++j) { s += e[j]; s2 += e[j] * e[j]; }
  #pragma unroll
  for (int off = 32; off; off >>= 1) { s += __shfl_xor(s, off); s2 += __shfl_xor(s2, off); }
  float mu = s * (1.f / 512.f);
  float var = s2 * (1.f / 512.f) - mu * mu;
  float rstd = rsqrtf(var + 1e-6f);
  int c0 = lane * 8;
  bf16x8 o;
  #pragma unroll
  for (int j = 0; j < 8; ++j) o[j] = f2b((e[j] - mu) * rstd * sc[c0 + j] + bi[c0 + j]);
  *((bf16x8*)(ob + (long)row * 512) + lane) = o;
}

// ---------------- LayerNorm, f32 in -> f32 out ----------------
__global__ __launch_bounds__(256) void k_ln_ff(const float* __restrict__ in, const float* __restrict__ sc,
                                               const float* __restrict__ bi, float* __restrict__ of)
{
  int row = blockIdx.x * 4 + (threadIdx.x >> 6);
  int lane = threadIdx.x & 63;
  const float* r = in + (long)row * 512;
  float4 a = *(const float4*)(r + lane * 4);
  float4 b = *(const float4*)(r + 256 + lane * 4);
  float s  = a.x + a.y + a.z + a.w + b.x + b.y + b.z + b.w;
  float s2 = a.x*a.x + a.y*a.y + a.z*a.z + a.w*a.w + b.x*b.x + b.y*b.y + b.z*b.z + b.w*b.w;
  #pragma unroll
  for (int off = 32; off; off >>= 1) { s += __shfl_xor(s, off); s2 += __shfl_xor(s2, off); }
  float mu = s * (1.f / 512.f);
  float var = s2 * (1.f / 512.f) - mu * mu;
  float rstd = rsqrtf(var + 1e-6f);
  int c0 = lane * 4;
  const float* ap = &a.x; const float* bp = &b.x;
  float o0[4], o1[4];
  #pragma unroll
  for (int j = 0; j < 4; ++j) {
    o0[j] = (ap[j] - mu) * rstd * sc[c0 + j]       + bi[c0 + j];
    o1[j] = (bp[j] - mu) * rstd * sc[256 + c0 + j] + bi[256 + c0 + j];
  }
  *(float4*)(of + (long)row * 512 + c0)       = (float4){o0[0], o0[1], o0[2], o0[3]};
  *(float4*)(of + (long)row * 512 + 256 + c0) = (float4){o1[0], o1[1], o1[2], o1[3]};
}

extern "C" void kernel_launch(void* const* d_in, const int* in_sizes, int n_in,
                              void* d_out, int out_size, void* d_ws, size_t ws_size,
                              hipStream_t stream)
{
  const float* x   = (const float*)d_in[0];
  const float* Wq  = (const float*)d_in[1];
  const float* bq  = (const float*)d_in[2];
  const float* Wk  = (const float*)d_in[3];
  const float* bk  = (const float*)d_in[4];
  const float* Wv  = (const float*)d_in[5];
  const float* bv  = (const float*)d_in[6];
  const float* Wo  = (const float*)d_in[7];
  const float* bo  = (const float*)d_in[8];
  const float* g1  = (const float*)d_in[9];
  const float* be1 = (const float*)d_in[10];
  const float* W1  = (const float*)d_in[11];
  const float* b1  = (const float*)d_in[12];
  const float* W2  = (const float*)d_in[13];
  const float* b2  = (const float*)d_in[14];
  const float* g2  = (const float*)d_in[15];
  const float* be2 = (const float*)d_in[16];
  float* out = (float*)d_out;

  const long MB = 1024L * 1024L;
  char* ws = (char*)d_ws;
  short* qp    = (short*)(ws + 0 * MB);     // 32 MiB; later hb
  short* kp    = (short*)(ws + 32 * MB);    // 32 MiB; later attn, then ffa lower
  short* vb    = (short*)(ws + 64 * MB);    // 32 MiB; later hpreB, then ffa upper
  short* attn  = (short*)(ws + 32 * MB);
  short* hb    = (short*)(ws + 0 * MB);
  short* hpreB = (short*)(ws + 64 * MB);    // 32 MiB bf16 h_pre (vb dead)
  short* ffa   = (short*)(ws + 32 * MB);    // 64 MiB [16384,2048] chunk (attn+hpreB dead)
  short* wqkvT = (short*)(ws + 96 * MB);    // 1.5 MiB [1536,512]
  short* woT   = (short*)(ws + 98 * MB);    // 0.5 MiB [512,512]
  short* w1T   = (short*)(ws + 99 * MB);    // 2 MiB   [2048,512]
  short* w2T   = (short*)(ws + 101 * MB);   // 2 MiB   [512,2048]
  short* kvt   = (short*)(ws + 103 * MB);   // 2 MiB   [BH,64,64]
  float* ksum  = (float*)(ws + 105 * MB);   // 64 KiB  [BH,64]
  float* bqkv  = (float*)(ws + 105 * MB + 65536);  // 6 KiB

  // d_out scratch: xb [0,32M), favor partials [32M,48.25M)
  short* xb  = (short*)d_out;
  float* kvp = (float*)((char*)d_out + 32 * MB);   // 16 MiB [4][256][64][64]
  float* ksp = (float*)((char*)d_out + 48 * MB);   // 256 KiB [4][256][64]

  dim3 tb(32, 8);
  k_cvt_x<<<8192, 256, 0, stream>>>(x, xb);
  k_tcvt4<<<dim3(16, 16, 4), tb, 0, stream>>>(Wq, Wk, Wv, Wo,
      wqkvT, wqkvT + 512 * 512, wqkvT + 1024 * 512, woT);
  k_tcvt<<<dim3(64, 16), tb, 0, stream>>>(W1, w1T, 512, 2048);
  k_tcvt<<<dim3(16, 64), tb, 0, stream>>>(W2, w2T, 2048, 512);
  k_pack_bias<<<6, 256, 0, stream>>>(bq, bk, bv, bqkv);

  // QKV projection: 256 m-tiles x 12 n-tiles
  k_gemm<0, 512><<<3072, 256, 0, stream>>>(xb, wqkvT, 12, bqkv, nullptr, nullptr, qp, kp, vb, nullptr);
  k_fkv_part<<<1024, 256, 0, stream>>>(kp, vb, kvp, ksp);
  k_fkv_reduce<<<4096, 256, 0, stream>>>(kvp, ksp, kvt, ksum);
  k_favor_num<<<2048, 256, 0, stream>>>(qp, kvt, ksum, attn);
  // attn-out + bo + x -> bf16 h_pre
  k_gemm<1, 512><<<1024, 256, 0, stream>>>(attn, woT, 4, bo, x, nullptr, hpreB, nullptr, nullptr, nullptr);
  k_ln_bb<<<8192, 256, 0, stream>>>(hpreB, g1, be1, hb);
  // FFN in 2 chunks of 16384 rows
  for (int c = 0; c < 2; ++c) {
    const short* hbc = hb + (long)c * 16384 * 512;
    k_gemm<2, 512><<<2048, 256, 0, stream>>>(hbc, w1T, 16, b1, nullptr, nullptr, ffa, nullptr, nullptr, nullptr);
    k_gemm<3, 2048><<<512, 256, 0, stream>>>(ffa, w2T, 4, b2, nullptr, hbc, nullptr, nullptr, nullptr, out + (long)c * 16384 * 512);
  }
  k_ln_ff<<<8192, 256, 0, stream>>>(out, g2, be2, out);
}

// Round 5
// 365.906 us; speedup vs baseline: 1.3634x; 1.1771x over previous
//
#include <hip/hip_runtime.h>

// Performer (FAVOR+) encoder block, bf16 MFMA pipeline. Round 5:
//  - 256x256-tile 8-wave GEMM, double-buffered 128 KiB LDS, 1 barrier/K-tile,
//    stage-before-compute (full-latency-cover drain), setprio around MFMA
//  - no FFN chunking: ffa split ws/d_out; FFN2 residual in-place into hb (bf16)
// B=32 L=1024 HID=512 H=8 DH=64 FF=2048, N=32768 tokens.
//
// ws (~106.1 MiB):
//   [0,32M)   qp  -> hb after favor_num (hb updated in-place by FFN2)
//   [32M,64M) kp  -> attn after favor_kv -> ffa rows<16384 (with next slot)
//   [64M,96M) vb  -> hpreB after favor   -> ffa rows<16384 (upper part)
//   [96M,..)  wqkvT, woT, w1T, w2T, kvt, ksum, bqkv
// d_out (64 MiB): xb bf16 [0,32M) + favor partials [32M,48.25M) early;
//   ffa rows>=16384 during FFN; final LN2 f32 output.

#define DI __device__ __forceinline__
#define AS1 __attribute__((address_space(1)))
#define AS3 __attribute__((address_space(3)))
#define GLD16(g, l) __builtin_amdgcn_global_load_lds((const AS1 void*)(g), (AS3 void*)(l), 16, 0, 0)

typedef __attribute__((ext_vector_type(8))) short bf16x8;
typedef __attribute__((ext_vector_type(4))) float f32x4;

DI float b2f(short s){ unsigned int u = ((unsigned int)(unsigned short)s) << 16; float f; __builtin_memcpy(&f, &u, 4); return f; }
DI short f2b(float f){ unsigned int u; __builtin_memcpy(&u, &f, 4); u += 0x7fffu + ((u >> 16) & 1u); return (short)(u >> 16); }

constexpr int Ll = 1024;
constexpr int SPLIT = 16384;   // row split between ws-resident and d_out-resident ffa

// ---------------- x -> bf16 ----------------
__global__ __launch_bounds__(256) void k_cvt_x(const float* __restrict__ x, short* __restrict__ xb){
  long i = (long)blockIdx.x * 256 + threadIdx.x;
  const float4* p = (const float4*)x + i * 2;
  float4 a = p[0], b = p[1];
  bf16x8 o;
  o[0]=f2b(a.x); o[1]=f2b(a.y); o[2]=f2b(a.z); o[3]=f2b(a.w);
  o[4]=f2b(b.x); o[5]=f2b(b.y); o[6]=f2b(b.z); o[7]=f2b(b.w);
  *((bf16x8*)xb + i) = o;
}

// ---------------- transpose + convert: in f32 [R][C] -> out bf16 [C][R] ----------------
__global__ void k_tcvt(const float* __restrict__ in, short* __restrict__ out, int R, int C){
  __shared__ float t[32][33];
  int c0 = blockIdx.x * 32, r0 = blockIdx.y * 32;
  int x = threadIdx.x, y = threadIdx.y;   // block (32,8)
  #pragma unroll
  for (int j = 0; j < 4; ++j) t[y + 8*j][x] = in[(long)(r0 + y + 8*j) * C + c0 + x];
  __syncthreads();
  #pragma unroll
  for (int j = 0; j < 4; ++j) out[(long)(c0 + y + 8*j) * R + r0 + x] = f2b(t[x][y + 8*j]);
}

// 4x [512,512] transposes in one launch (z picks matrix)
__global__ void k_tcvt4(const float* __restrict__ s0, const float* __restrict__ s1,
                        const float* __restrict__ s2, const float* __restrict__ s3,
                        short* __restrict__ d0, short* __restrict__ d1,
                        short* __restrict__ d2, short* __restrict__ d3){
  __shared__ float t[32][33];
  int z = blockIdx.z;
  const float* in = z == 0 ? s0 : z == 1 ? s1 : z == 2 ? s2 : s3;
  short* out      = z == 0 ? d0 : z == 1 ? d1 : z == 2 ? d2 : d3;
  int c0 = blockIdx.x * 32, r0 = blockIdx.y * 32;
  int x = threadIdx.x, y = threadIdx.y;
  #pragma unroll
  for (int j = 0; j < 4; ++j) t[y + 8*j][x] = in[(long)(r0 + y + 8*j) * 512 + c0 + x];
  __syncthreads();
  #pragma unroll
  for (int j = 0; j < 4; ++j) out[(long)(c0 + y + 8*j) * 512 + r0 + x] = f2b(t[x][y + 8*j]);
}

__global__ void k_pack_bias(const float* __restrict__ bq, const float* __restrict__ bk,
                            const float* __restrict__ bv, float* __restrict__ bqkv){
  int i = blockIdx.x * 256 + threadIdx.x;
  if (i < 512) bqkv[i] = bq[i];
  else if (i < 1024) bqkv[i] = bk[i - 512];
  else if (i < 1536) bqkv[i] = bv[i - 1024];
}

// ---------------- 256x256 bf16 MFMA GEMM, 8 waves, dbuf LDS, 1 barrier/K-tile ----
// A [M,KD] bf16 row-major (A1 used for global rows >= SPLIT when A1 != A0).
// BT [NT*256,KD] bf16 row-major. Grid 1D, G = MT*NT (G%8==0), XCD swizzle.
// LDS (128 KiB): A[buf][half][128][64] | B[buf][half][128][64], 16B slot s of row r
// holds global chunk s^(r&7) (involution; conflict-free ds_read_b128).
// EPI: 0=QKV(phi->qp,kp,vb)  1=attn-out(+bo+x(f32) -> bf16 oQ)
//      2=FFN1(relu -> bf16 oQ/o1 row-split, stride 2048)  3=FFN2(+bias+oQ, in-place bf16 oQ)
template<int EPI, int KD>
__global__ __launch_bounds__(512, 2) void k_gemm256(
    const short* __restrict__ A0, const short* __restrict__ A1,
    const short* __restrict__ BT, int NT,
    const float* __restrict__ bias, const float* __restrict__ residF,
    short* __restrict__ oQ, short* __restrict__ oK, short* __restrict__ oV,
    short* __restrict__ o1)
{
  __shared__ short lds[65536];              // 128 KiB
  const int tid = threadIdx.x;
  const int w = tid >> 6, lane = tid & 63;
  const int wm = w >> 2, wn = w & 3;        // 2M x 4N wave grid; per-wave out 128x64
  const int lg = lane >> 4, lr = lane & 15;
  const int lrow = lane >> 3, lslot = (lane & 7) ^ lrow;

  const int per = gridDim.x >> 3;
  const int wg = (blockIdx.x & 7) * per + (blockIdx.x >> 3);
  const long m0 = (long)(wg / NT) * 256, n0 = (long)(wg % NT) * 256;

  const short* Ause = A0;
  long mbase = m0;
  if (A1 != A0 && m0 >= SPLIT) { Ause = A1; mbase = m0 - SPLIT; }

  f32x4 acc[8][4];
  #pragma unroll
  for (int i = 0; i < 8; ++i)
    #pragma unroll
    for (int j = 0; j < 4; ++j) acc[i][j] = 0.f;

  // short-index bases: A(buf,half)=buf*16384+half*8192; B: +32768
  auto stage_all = [&](int buf, int k0){
    #pragma unroll
    for (int half = 0; half < 2; ++half)
      #pragma unroll
      for (int q = 0; q < 2; ++q) {
        int r = w * 16 + q * 8;
        GLD16(Ause + (mbase + half * 128 + r + lrow) * KD + k0 + lslot * 8,
              (char*)lds + (buf * 16384 + half * 8192 + r * 64) * 2);
        GLD16(BT + (n0 + half * 128 + r + lrow) * KD + k0 + lslot * 8,
              (char*)lds + (32768 + buf * 16384 + half * 8192 + r * 64) * 2);
      }
  };

  constexpr int NKT = KD / 64;
  stage_all(0, 0);                          // prologue: K-tile 0 -> buf 0

  for (int kt = 0; kt < NKT; ++kt) {
    const int cur = kt & 1;
    __syncthreads();                        // drains buf[cur] staging; prior reads retired
    if (kt + 1 < NKT) stage_all(cur ^ 1, (kt + 1) * 64);

    const char* Ab = (const char*)lds + (cur * 16384 + wm * 8192) * 2;
    const char* Bb = (const char*)lds + (32768 + cur * 16384 + (wn >> 1) * 8192) * 2;

    bf16x8 fB[2][2][2];                     // [qc][j][kk] held for whole K-tile
    #pragma unroll
    for (int qc = 0; qc < 2; ++qc)
      #pragma unroll
      for (int j = 0; j < 2; ++j)
        #pragma unroll
        for (int kk = 0; kk < 2; ++kk) {
          int rb = (wn & 1) * 64 + qc * 32 + j * 16 + lr;
          fB[qc][j][kk] = *(const bf16x8*)(Bb + rb * 128 + ((kk * 64 + lg * 16) ^ ((rb & 7) << 4)));
        }
    #pragma unroll
    for (int qr = 0; qr < 2; ++qr) {
      bf16x8 fA[4][2];
      #pragma unroll
      for (int i = 0; i < 4; ++i)
        #pragma unroll
        for (int kk = 0; kk < 2; ++kk) {
          int ra = qr * 64 + i * 16 + lr;
          fA[i][kk] = *(const bf16x8*)(Ab + ra * 128 + ((kk * 64 + lg * 16) ^ ((ra & 7) << 4)));
        }
      __builtin_amdgcn_s_setprio(1);
      #pragma unroll
      for (int i = 0; i < 4; ++i)
        #pragma unroll
        for (int qc = 0; qc < 2; ++qc)
          #pragma unroll
          for (int j = 0; j < 2; ++j)
            #pragma unroll
            for (int kk = 0; kk < 2; ++kk)
              acc[qr * 4 + i][qc * 2 + j] =
                __builtin_amdgcn_mfma_f32_16x16x32_bf16(fA[i][kk], fB[qc][j][kk], acc[qr * 4 + i][qc * 2 + j], 0, 0, 0);
      __builtin_amdgcn_s_setprio(0);
    }
  }

  #pragma unroll
  for (int fr = 0; fr < 8; ++fr)
    #pragma unroll
    for (int fc = 0; fc < 4; ++fc)
      #pragma unroll
      for (int r = 0; r < 4; ++r) {
        int grow = (int)m0 + wm * 128 + fr * 16 + lg * 4 + r;  // C/D: row=(lane>>4)*4+reg
        int gcol = (int)n0 + wn * 64 + fc * 16 + lr;           //      col=lane&15
        float v = acc[fr][fc][r];
        if constexpr (EPI == 0) {
          v += bias[gcol];
          int which = gcol >> 9, hd = gcol & 511, h = hd >> 6, d = hd & 63;
          int b = grow >> 10, l = grow & 1023;
          long o = ((long)(b * 8 + h) * 1024 + l) * 64 + d;
          if (which == 2) oV[o] = f2b(v);
          else { float p = fmaxf(v, 0.f) + 1e-3f; if (which) oK[o] = f2b(p); else oQ[o] = f2b(p); }
        } else if constexpr (EPI == 1) {
          v += bias[gcol] + residF[(long)grow * 512 + gcol];
          oQ[(long)grow * 512 + gcol] = f2b(v);
        } else if constexpr (EPI == 2) {
          v = fmaxf(v + bias[gcol], 0.f);
          if (grow < SPLIT) oQ[(long)grow * 2048 + gcol] = f2b(v);
          else              o1[(long)(grow - SPLIT) * 2048 + gcol] = f2b(v);
        } else {
          long idx = (long)grow * 512 + gcol;
          v += bias[gcol] + b2f(oQ[idx]);
          oQ[idx] = f2b(v);
        }
      }
}

// ---------------- FAVOR kv partials: chunk c sums l in [c*256, c*256+256) ----------------
__global__ __launch_bounds__(256) void k_fkv_part(const short* __restrict__ kp, const short* __restrict__ vb,
                                                  float* __restrict__ kvp, float* __restrict__ ksp)
{
  constexpr int LS = 72;
  __shared__ short kps[64 * LS];
  __shared__ short vps[64 * LS];
  int bh = blockIdx.x & 255, c = blockIdx.x >> 8;
  const short* kpp = kp + (long)bh * Ll * 64;
  const short* vpp = vb + (long)bh * Ll * 64;
  int tid = threadIdx.x;
  int mb = (tid & 15) * 4, db = (tid >> 4) * 4;
  float acc[4][4];
  float ks[4] = {0.f, 0.f, 0.f, 0.f};
  #pragma unroll
  for (int i = 0; i < 4; ++i)
    #pragma unroll
    for (int j = 0; j < 4; ++j) acc[i][j] = 0.f;

  for (int l0 = c * 256; l0 < c * 256 + 256; l0 += 64) {
    __syncthreads();
    #pragma unroll
    for (int s = 0; s < 2; ++s) {
      int idx = tid + s * 256;
      int row = idx >> 3, c8 = idx & 7;
      *(bf16x8*)(&kps[row * LS + c8 * 8]) = *(const bf16x8*)(kpp + (long)(l0 + row) * 64 + c8 * 8);
      *(bf16x8*)(&vps[row * LS + c8 * 8]) = *(const bf16x8*)(vpp + (long)(l0 + row) * 64 + c8 * 8);
    }
    __syncthreads();
    #pragma unroll 4
    for (int l = 0; l < 64; ++l) {
      short4 ka = *(const short4*)(&kps[l * LS + mb]);
      short4 va = *(const short4*)(&vps[l * LS + db]);
      float kf[4] = {b2f(ka.x), b2f(ka.y), b2f(ka.z), b2f(ka.w)};
      float vf[4] = {b2f(va.x), b2f(va.y), b2f(va.z), b2f(va.w)};
      if (tid < 16) { ks[0] += kf[0]; ks[1] += kf[1]; ks[2] += kf[2]; ks[3] += kf[3]; }
      #pragma unroll
      for (int i = 0; i < 4; ++i)
        #pragma unroll
        for (int j = 0; j < 4; ++j) acc[i][j] += kf[i] * vf[j];
    }
  }
  float* kout = kvp + (long)c * 1048576 + (long)bh * 4096;
  #pragma unroll
  for (int i = 0; i < 4; ++i)
    #pragma unroll
    for (int j = 0; j < 4; ++j)
      kout[(db + j) * 64 + mb + i] = acc[i][j];
  if (tid < 16) {
    #pragma unroll
    for (int i = 0; i < 4; ++i) ksp[(long)c * 16384 + bh * 64 + mb + i] = ks[i];
  }
}

__global__ __launch_bounds__(256) void k_fkv_reduce(const float* __restrict__ kvp, const float* __restrict__ ksp,
                                                    short* __restrict__ kvt, float* __restrict__ ksum)
{
  int g = blockIdx.x * 256 + threadIdx.x;
  float s = kvp[g] + kvp[g + 1048576] + kvp[g + 2 * 1048576] + kvp[g + 3 * 1048576];
  kvt[g] = f2b(s);
  if (g < 16384)
    ksum[g] = ksp[g] + ksp[g + 16384] + ksp[g + 2 * 16384] + ksp[g + 3 * 16384];
}

// ---------------- FAVOR: attn = (qp @ kv)/den ----------------
__global__ __launch_bounds__(256) void k_favor_num(const short* __restrict__ qp, const short* __restrict__ kvt,
                                                   const float* __restrict__ ksum, short* __restrict__ attn)
{
  constexpr int LS = 72;
  __shared__ short Qs[128 * 64];
  __shared__ short kvs[64 * LS];
  __shared__ float part[256];
  __shared__ float den[128];
  int bh = blockIdx.x >> 3, lt = blockIdx.x & 7;
  int b = bh >> 3, h = bh & 7;
  const short* qpp = qp + ((long)bh * Ll + lt * 128) * 64;
  int tid = threadIdx.x;
  int wave = tid >> 6, lane = tid & 63;
  int lrow = lane >> 3, lslot = (lane & 7) ^ lrow;

  #pragma unroll
  for (int s = 0; s < 4; ++s) {
    int rs = (s * 4 + wave) * 8;
    GLD16(qpp + (long)(rs + lrow) * 64 + lslot * 8, &Qs[rs * 64]);
  }
  #pragma unroll
  for (int s = 0; s < 2; ++s) {
    int idx = tid + s * 256;
    int row = idx >> 3, c8 = idx & 7;
    *(bf16x8*)(&kvs[row * LS + c8 * 8]) = *(const bf16x8*)(kvt + (long)bh * 4096 + row * 64 + c8 * 8);
  }
  __syncthreads();
  {
    int r = tid >> 1, half = tid & 1;
    const float* kss = ksum + bh * 64 + half * 32;
    float s = 0.f;
    #pragma unroll
    for (int c = 0; c < 4; ++c) {
      int cc = half * 4 + c;
      bf16x8 v = *(const bf16x8*)((const char*)Qs + r * 128 + ((cc * 16) ^ ((r & 7) << 4)));
      #pragma unroll
      for (int j = 0; j < 8; ++j) s += b2f(v[j]) * kss[c * 8 + j];
    }
    part[tid] = s;
  }
  __syncthreads();
  if (tid < 128) den[tid] = part[2 * tid] + part[2 * tid + 1];
  __syncthreads();

  int wr = wave >> 1, wc = wave & 1;
  int lg = lane >> 4, lr = lane & 15;
  f32x4 acc[4][2];
  #pragma unroll
  for (int i = 0; i < 4; ++i) { acc[i][0] = 0.f; acc[i][1] = 0.f; }
  #pragma unroll
  for (int kk = 0; kk < 2; ++kk) {
    bf16x8 af[4], bfr[2];
    #pragma unroll
    for (int i = 0; i < 4; ++i) {
      int ra = wr * 64 + i * 16 + lr;
      af[i] = *(const bf16x8*)((const char*)Qs + ra * 128 + ((kk * 64 + lg * 16) ^ ((ra & 7) << 4)));
    }
    #pragma unroll
    for (int j = 0; j < 2; ++j)
      bfr[j] = *(const bf16x8*)(&kvs[(wc * 32 + j * 16 + lr) * LS + kk * 32 + lg * 8]);
    #pragma unroll
    for (int i = 0; i < 4; ++i)
      #pragma unroll
      for (int j = 0; j < 2; ++j)
        acc[i][j] = __builtin_amdgcn_mfma_f32_16x16x32_bf16(af[i], bfr[j], acc[i][j], 0, 0, 0);
  }
  #pragma unroll
  for (int i = 0; i < 4; ++i)
    #pragma unroll
    for (int j = 0; j < 2; ++j)
      #pragma unroll
      for (int r = 0; r < 4; ++r) {
        int rl = wr * 64 + i * 16 + lg * 4 + r;
        int d  = wc * 32 + j * 16 + lr;
        int t  = b * Ll + lt * 128 + rl;
        attn[(long)t * 512 + h * 64 + d] = f2b(acc[i][j][r] / den[rl]);
      }
}

// ---------------- LayerNorm, bf16 in -> bf16 out (one wave per row of 512) ----------------
__global__ __launch_bounds__(256) void k_ln_bb(const short* __restrict__ in, const float* __restrict__ sc,
                                               const float* __restrict__ bi, short* __restrict__ ob)
{
  int row = blockIdx.x * 4 + (threadIdx.x >> 6);
  int lane = threadIdx.x & 63;
  bf16x8 v = *((const bf16x8*)(in + (long)row * 512) + lane);
  float e[8];
  #pragma unroll
  for (int j = 0; j < 8; ++j) e[j] = b2f(v[j]);
  float s = 0.f, s2 = 0.f;
  #pragma unroll
  for (int j = 0; j < 8; ++j) { s += e[j]; s2 += e[j] * e[j]; }
  #pragma unroll
  for (int off = 32; off; off >>= 1) { s += __shfl_xor(s, off); s2 += __shfl_xor(s2, off); }
  float mu = s * (1.f / 512.f);
  float var = s2 * (1.f / 512.f) - mu * mu;
  float rstd = rsqrtf(var + 1e-6f);
  int c0 = lane * 8;
  bf16x8 o;
  #pragma unroll
  for (int j = 0; j < 8; ++j) o[j] = f2b((e[j] - mu) * rstd * sc[c0 + j] + bi[c0 + j]);
  *((bf16x8*)(ob + (long)row * 512) + lane) = o;
}

// ---------------- LayerNorm, bf16 in -> f32 out ----------------
__global__ __launch_bounds__(256) void k_ln_bf(const short* __restrict__ in, const float* __restrict__ sc,
                                               const float* __restrict__ bi, float* __restrict__ of)
{
  int row = blockIdx.x * 4 + (threadIdx.x >> 6);
  int lane = threadIdx.x & 63;
  bf16x8 v = *((const bf16x8*)(in + (long)row * 512) + lane);
  float e[8];
  #pragma unroll
  for (int j = 0; j < 8; ++j) e[j] = b2f(v[j]);
  float s = 0.f, s2 = 0.f;
  #pragma unroll
  for (int j = 0; j < 8; ++j) { s += e[j]; s2 += e[j] * e[j]; }
  #pragma unroll
  for (int off = 32; off; off >>= 1) { s += __shfl_xor(s, off); s2 += __shfl_xor(s2, off); }
  float mu = s * (1.f / 512.f);
  float var = s2 * (1.f / 512.f) - mu * mu;
  float rstd = rsqrtf(var + 1e-6f);
  int c0 = lane * 8;
  float o0[4], o1[4];
  #pragma unroll
  for (int j = 0; j < 4; ++j) {
    o0[j] = (e[j]     - mu) * rstd * sc[c0 + j]     + bi[c0 + j];
    o1[j] = (e[4 + j] - mu) * rstd * sc[c0 + 4 + j] + bi[c0 + 4 + j];
  }
  *(float4*)(of + (long)row * 512 + c0)     = (float4){o0[0], o0[1], o0[2], o0[3]};
  *(float4*)(of + (long)row * 512 + c0 + 4) = (float4){o1[0], o1[1], o1[2], o1[3]};
}

extern "C" void kernel_launch(void* const* d_in, const int* in_sizes, int n_in,
                              void* d_out, int out_size, void* d_ws, size_t ws_size,
                              hipStream_t stream)
{
  const float* x   = (const float*)d_in[0];
  const float* Wq  = (const float*)d_in[1];
  const float* bq  = (const float*)d_in[2];
  const float* Wk  = (const float*)d_in[3];
  const float* bk  = (const float*)d_in[4];
  const float* Wv  = (const float*)d_in[5];
  const float* bv  = (const float*)d_in[6];
  const float* Wo  = (const float*)d_in[7];
  const float* bo  = (const float*)d_in[8];
  const float* g1  = (const float*)d_in[9];
  const float* be1 = (const float*)d_in[10];
  const float* W1  = (const float*)d_in[11];
  const float* b1  = (const float*)d_in[12];
  const float* W2  = (const float*)d_in[13];
  const float* b2  = (const float*)d_in[14];
  const float* g2  = (const float*)d_in[15];
  const float* be2 = (const float*)d_in[16];
  float* out = (float*)d_out;

  const long MB = 1024L * 1024L;
  char* ws = (char*)d_ws;
  short* qp    = (short*)(ws + 0 * MB);     // 32 MiB; later hb (FFN2 updates in place)
  short* kp    = (short*)(ws + 32 * MB);    // 32 MiB; later attn, then ffa0 (low)
  short* vb    = (short*)(ws + 64 * MB);    // 32 MiB; later hpreB, then ffa0 (high)
  short* attn  = (short*)(ws + 32 * MB);
  short* hb    = (short*)(ws + 0 * MB);
  short* hpreB = (short*)(ws + 64 * MB);
  short* ffa0  = (short*)(ws + 32 * MB);    // 64 MiB: rows [0,16384) x 2048 bf16
  short* wqkvT = (short*)(ws + 96 * MB);    // 1.5 MiB [1536,512]
  short* woT   = (short*)(ws + 98 * MB);    // 0.5 MiB [512,512]
  short* w1T   = (short*)(ws + 99 * MB);    // 2 MiB   [2048,512]
  short* w2T   = (short*)(ws + 101 * MB);   // 2 MiB   [512,2048]
  short* kvt   = (short*)(ws + 103 * MB);   // 2 MiB   [BH,64,64]
  float* ksum  = (float*)(ws + 105 * MB);   // 64 KiB
  float* bqkv  = (float*)(ws + 105 * MB + 65536);

  // d_out scratch: xb [0,32M), favor partials [32M,48.25M), later ffa1 [0,64M)
  short* xb   = (short*)d_out;
  float* kvp  = (float*)((char*)d_out + 32 * MB);
  float* ksp  = (float*)((char*)d_out + 48 * MB);
  short* ffa1 = (short*)d_out;              // rows [16384,32768) x 2048 bf16

  dim3 tb(32, 8);
  k_cvt_x<<<8192, 256, 0, stream>>>(x, xb);
  k_tcvt4<<<dim3(16, 16, 4), tb, 0, stream>>>(Wq, Wk, Wv, Wo,
      wqkvT, wqkvT + 512 * 512, wqkvT + 1024 * 512, woT);
  k_tcvt<<<dim3(64, 16), tb, 0, stream>>>(W1, w1T, 512, 2048);
  k_tcvt<<<dim3(16, 64), tb, 0, stream>>>(W2, w2T, 2048, 512);
  k_pack_bias<<<6, 256, 0, stream>>>(bq, bk, bv, bqkv);

  // QKV projection: 128 m-tiles x 6 n-tiles = 768 blocks
  k_gemm256<0, 512><<<768, 512, 0, stream>>>(xb, xb, wqkvT, 6, bqkv, nullptr, qp, kp, vb, nullptr);
  k_fkv_part<<<1024, 256, 0, stream>>>(kp, vb, kvp, ksp);
  k_fkv_reduce<<<4096, 256, 0, stream>>>(kvp, ksp, kvt, ksum);
  k_favor_num<<<2048, 256, 0, stream>>>(qp, kvt, ksum, attn);
  // attn-out + bo + x -> bf16 hpreB: 128 x 2 = 256 blocks
  k_gemm256<1, 512><<<256, 512, 0, stream>>>(attn, attn, woT, 2, bo, x, hpreB, nullptr, nullptr, nullptr);
  k_ln_bb<<<8192, 256, 0, stream>>>(hpreB, g1, be1, hb);
  // FFN1: 128 x 8 = 1024 blocks, output row-split ffa0/ffa1
  k_gemm256<2, 512><<<1024, 512, 0, stream>>>(hb, hb, w1T, 8, b1, nullptr, ffa0, nullptr, nullptr, ffa1);
  // FFN2: 128 x 2 = 256 blocks, A row-split, residual in-place into hb
  k_gemm256<3, 2048><<<256, 512, 0, stream>>>(ffa0, ffa1, w2T, 2, b2, nullptr, hb, nullptr, nullptr, nullptr);
  k_ln_bf<<<8192, 256, 0, stream>>>(hb, g2, be2, out);
}